// Round 7
// baseline (321.957 us; speedup 1.0000x reference)
//
#include <hip/hip_runtime.h>

#define N_NODES 50000
#define N_EDGES 1600000
#define IN_DIM  256
#define OUT_D   128   // N_HEADS * OUT_DIM
#define NEG_SLOPE 0.2f
#define PART 6250     // N_NODES / 8 (dst-partition per XCD)
#define NP 50176      // N_NODES padded to 49*1024 (scan tiles, no tail guards)
#define SCAN_NB 49
#define CAPP 204800   // per-partition edge capacity (mean 200000, +11.5 sigma)

typedef unsigned short ushort_t;
typedef short bf16x8 __attribute__((ext_vector_type(8)));
typedef float f32x4 __attribute__((ext_vector_type(4)));

__device__ __forceinline__ ushort_t f2bf(float f) {
    unsigned u = __float_as_uint(f);
    u = (u + 0x7FFF + ((u >> 16) & 1)) >> 16;   // RNE
    return (ushort_t)u;
}

// ---------------------------------------------------------------------------
// K0b: W fp32 [256][128] -> wt bf16, transposed n-major with 16B XOR swizzle.
__global__ __launch_bounds__(256) void wprep_kernel(const float* __restrict__ W,
                                                    ushort_t* __restrict__ wt) {
    int i0 = (blockIdx.x * 256 + threadIdx.x) * 4;   // grid 32 -> covers 32768
    f32x4 v = *(const f32x4*)(W + i0);
    int k = i0 >> 7;
    int n0 = i0 & 127;
    int byte_in_row = 2 * k;
#pragma unroll
    for (int j = 0; j < 4; ++j) {
        int n = n0 + j;
        int sw = ((byte_in_row & ~15) ^ ((n & 7) << 4)) | (byte_in_row & 15);
        wt[(n << 8) + (sw >> 1)] = f2bf(v[j]);
    }
}

// ---------------------------------------------------------------------------
// K1: h_prime = bf16(h) @ bf16(W) via MFMA; epilogue also produces asrc/adst
//     attention logit halves from the fp32 accumulators.
__global__ __launch_bounds__(256) void gemm_kernel(const float* __restrict__ h,
                                                   const ushort_t* __restrict__ wt,
                                                   const float* __restrict__ a,
                                                   ushort_t* __restrict__ hp,
                                                   float* __restrict__ asrc,
                                                   float* __restrict__ adst) {
    __shared__ ushort_t sW[32768];  // 64 KB
    int t = threadIdx.x;
    for (int i = t * 8; i < 32768; i += 2048)
        *(bf16x8*)(sW + i) = *(const bf16x8*)(wt + i);
    __syncthreads();

    int wave = t >> 6, lane = t & 63;
    int l15 = lane & 15, quad = lane >> 4;
    int rowbase = blockIdx.x * 128 + wave * 16;

    f32x4 acc[2][8] = {};
#pragma unroll
    for (int ks = 0; ks < 8; ++ks) {
        bf16x8 af[2];
#pragma unroll
        for (int rt = 0; rt < 2; ++rt) {
            int arow = rowbase + rt * 64 + l15;
            if (arow >= N_NODES) arow = N_NODES - 1;
            const float* ap = h + (size_t)arow * IN_DIM + quad * 8 + ks * 32;
            f32x4 lo = *(const f32x4*)ap;
            f32x4 hi = *(const f32x4*)(ap + 4);
#pragma unroll
            for (int j = 0; j < 4; ++j) {
                af[rt][j]     = (short)f2bf(lo[j]);
                af[rt][4 + j] = (short)f2bf(hi[j]);
            }
        }
        int koff = ks * 64 + quad * 16;
#pragma unroll
        for (int tn = 0; tn < 8; ++tn) {
            int n = tn * 16 + l15;
            int swz = koff ^ ((n & 7) << 4);
            bf16x8 bfr = *(const bf16x8*)((const char*)sW + n * 512 + swz);
            acc[0][tn] = __builtin_amdgcn_mfma_f32_16x16x32_bf16(af[0], bfr, acc[0][tn], 0, 0, 0);
            acc[1][tn] = __builtin_amdgcn_mfma_f32_16x16x32_bf16(af[1], bfr, acc[1][tn], 0, 0, 0);
        }
    }

    // a-vector weights for this lane's 8 columns (col = tn*16 + l15)
    float aS[8], aD[8];
#pragma unroll
    for (int tn = 0; tn < 8; ++tn) {
        int col = tn * 16 + l15;
        int dd = col & 31, hh = col >> 5;
        aS[tn] = a[dd * 4 + hh];
        aD[tn] = a[(32 + dd) * 4 + hh];
    }

#pragma unroll
    for (int rt = 0; rt < 2; ++rt)
#pragma unroll
        for (int r = 0; r < 4; ++r) {
            int row = rowbase + rt * 64 + quad * 4 + r;
            float pS[4] = {0.f, 0.f, 0.f, 0.f}, pD[4] = {0.f, 0.f, 0.f, 0.f};
#pragma unroll
            for (int tn = 0; tn < 8; ++tn) {
                float v = acc[rt][tn][r];
                pS[tn >> 1] += v * aS[tn];
                pD[tn >> 1] += v * aD[tn];
            }
#pragma unroll
            for (int o = 1; o < 16; o <<= 1) {
#pragma unroll
                for (int hh = 0; hh < 4; ++hh) {
                    pS[hh] += __shfl_xor(pS[hh], o, 16);
                    pD[hh] += __shfl_xor(pD[hh], o, 16);
                }
            }
            if (row < N_NODES) {
                if (l15 == 0) { f32x4 v = {pS[0], pS[1], pS[2], pS[3]}; *(f32x4*)(asrc + row * 4) = v; }
                if (l15 == 1) { f32x4 v = {pD[0], pD[1], pD[2], pD[3]}; *(f32x4*)(adst + row * 4) = v; }
            }
        }

#pragma unroll
    for (int rt = 0; rt < 2; ++rt)
#pragma unroll
        for (int tn = 0; tn < 8; ++tn) {
            int col = tn * 16 + l15;
#pragma unroll
            for (int r = 0; r < 4; ++r) {
                int row = rowbase + rt * 64 + quad * 4 + r;
                if (row < N_NODES) hp[(size_t)row * OUT_D + col] = f2bf(acc[rt][tn][r]);
            }
        }
}

// ---------------------------------------------------------------------------
// K3 (pass A): one read of adj -> per-XCD degree histogram (merged old hist)
//   + edges binned by dst-partition into 8 private buffers, COALESCED writes.
//   One global atomic per (block, partition) to reserve space.
__global__ __launch_bounds__(256) void bin_kernel(const int* __restrict__ src,
                                                  const int* __restrict__ dst,
                                                  int* __restrict__ deg8,
                                                  int* __restrict__ tail8,
                                                  uint2* __restrict__ binbuf) {
    __shared__ uint2 stage[2048];       // 16 KB
    __shared__ int cnt[8], lcnt[8], lbase[9], gbase[8];
    int t = threadIdx.x;
    if (t < 8) { cnt[t] = 0; lcnt[t] = 0; }
    __syncthreads();

    int blockbase = blockIdx.x * 2048;
    int n = min(2048, N_EDGES - blockbase);
    int e0 = blockbase + t * 8;
    int d[8], s[8], myp[8];
    if (t * 8 + 8 <= n) {
        int4 a = *(const int4*)(dst + e0);
        int4 b = *(const int4*)(dst + e0 + 4);
        d[0]=a.x; d[1]=a.y; d[2]=a.z; d[3]=a.w;
        d[4]=b.x; d[5]=b.y; d[6]=b.z; d[7]=b.w;
        int4 c = *(const int4*)(src + e0);
        int4 e = *(const int4*)(src + e0 + 4);
        s[0]=c.x; s[1]=c.y; s[2]=c.z; s[3]=c.w;
        s[4]=e.x; s[5]=e.y; s[6]=e.z; s[7]=e.w;
    } else {
#pragma unroll
        for (int j = 0; j < 8; ++j) {
            bool ok = (t * 8 + j < n);
            d[j] = ok ? dst[e0 + j] : -1;
            s[j] = ok ? src[e0 + j] : 0;
        }
    }
    int* mydeg = deg8 + (blockIdx.x & 7) * NP;
#pragma unroll
    for (int j = 0; j < 8; ++j) {
        if (d[j] >= 0) {
            atomicAdd(&mydeg[d[j]], 1);
            myp[j] = d[j] / PART;
            atomicAdd(&cnt[myp[j]], 1);
        } else myp[j] = -1;
    }
    __syncthreads();
    if (t == 0) {
        lbase[0] = 0;
        for (int p = 0; p < 8; ++p) lbase[p + 1] = lbase[p] + cnt[p];
    }
    if (t < 8) gbase[t] = atomicAdd(&tail8[t], cnt[t]);
    __syncthreads();
#pragma unroll
    for (int j = 0; j < 8; ++j) {
        if (myp[j] >= 0) {
            int pos = lbase[myp[j]] + atomicAdd(&lcnt[myp[j]], 1);
            stage[pos].x = (unsigned)s[j];
            stage[pos].y = (unsigned)d[j];
        }
    }
    __syncthreads();
    for (int i = t; i < n; i += 256) {
        uint2 v = stage[i];
        int p = 0;
#pragma unroll
        for (int q = 1; q < 8; ++q) p += (i >= lbase[q]);
        binbuf[(size_t)p * CAPP + gbase[p] + (i - lbase[p])] = v;
    }
}

// ---------------------------------------------------------------------------
// K4a: sum 8 histogram copies -> deg[], and per-tile sums
__global__ __launch_bounds__(256) void scan_part_kernel(const int* __restrict__ deg8,
                                                        int* __restrict__ deg,
                                                        int* __restrict__ bsum) {
    int t = threadIdx.x;
    int base = blockIdx.x * 1024 + t * 4;
    int4 v = {0, 0, 0, 0};
#pragma unroll
    for (int p = 0; p < 8; ++p) {
        int4 u = *(const int4*)(deg8 + p * NP + base);
        v.x += u.x; v.y += u.y; v.z += u.z; v.w += u.w;
    }
    *(int4*)(deg + base) = v;
    int s = v.x + v.y + v.z + v.w;
#pragma unroll
    for (int o = 32; o > 0; o >>= 1) s += __shfl_down(s, o, 64);
    __shared__ int ws[4];
    if ((t & 63) == 0) ws[t >> 6] = s;
    __syncthreads();
    if (t == 0) bsum[blockIdx.x] = ws[0] + ws[1] + ws[2] + ws[3];
}

// K4b: exclusive scan of the 49 tile sums (single wave)
__global__ __launch_bounds__(64) void scan_top_kernel(const int* __restrict__ bsum,
                                                      int* __restrict__ bbase) {
    int t = threadIdx.x;
    int v = (t < SCAN_NB) ? bsum[t] : 0;
    int inc = v;
#pragma unroll
    for (int o = 1; o < 64; o <<= 1) {
        int u = __shfl_up(inc, o, 64);
        if (t >= o) inc += u;
    }
    if (t < SCAN_NB) bbase[t] = inc - v;
}

// K4c: in-tile exclusive scan + base -> off[], cursor[]
__global__ __launch_bounds__(256) void scan_final_kernel(const int* __restrict__ deg,
                                                         const int* __restrict__ bbase,
                                                         int* __restrict__ off,
                                                         int* __restrict__ cursor) {
    int t = threadIdx.x;
    int base = blockIdx.x * 1024 + t * 4;
    int4 v = *(const int4*)(deg + base);
    int lsum = v.x + v.y + v.z + v.w;
    int inc = lsum;
    int l64 = t & 63;
#pragma unroll
    for (int o = 1; o < 64; o <<= 1) {
        int u = __shfl_up(inc, o, 64);
        if (l64 >= o) inc += u;
    }
    __shared__ int ws[4];
    if (l64 == 63) ws[t >> 6] = inc;
    __syncthreads();
    int woff = 0;
    for (int w = 0; w < (t >> 6); ++w) woff += ws[w];
    int ex = bbase[blockIdx.x] + woff + inc - lsum;
    int4 o4;
    o4.x = ex;
    o4.y = ex + v.x;
    o4.z = ex + v.x + v.y;
    o4.w = ex + v.x + v.y + v.z;
    *(int4*)(off + base) = o4;
    *(int4*)(cursor + base) = o4;
}

// ---------------------------------------------------------------------------
// K5 (pass B): fine scatter, fully XCD-local. Per XCD: 1.6 MB read stream +
//   800 KB dirty csr + 25 KB cursors all fit in the 4 MB L2 -> lines complete.
__global__ __launch_bounds__(256) void scatter2_kernel(const uint2* __restrict__ binbuf,
                                                       const int* __restrict__ tail8,
                                                       int* __restrict__ cursor,
                                                       int* __restrict__ csr) {
    int p = blockIdx.x & 7;
    int nb = gridDim.x >> 3;
    int bi = blockIdx.x >> 3;
    int count = tail8[p];
    int chunk = (count + nb - 1) / nb;
    int lo = bi * chunk, hi = min(lo + chunk, count);
    const uint2* buf = binbuf + (size_t)p * CAPP;
    for (int i = lo + threadIdx.x; i < hi; i += 256) {
        uint2 e = buf[i];
        int pos = atomicAdd(&cursor[e.y], 1);
        csr[pos] = (int)e.x;
    }
}

// ---------------------------------------------------------------------------
// K6: softmax without max-subtraction (clamped), one wave per node.
__global__ __launch_bounds__(256) void agg_kernel(const int* __restrict__ off,
                                                  const int* __restrict__ csr,
                                                  const float* __restrict__ asrc,
                                                  const float* __restrict__ adst,
                                                  const ushort_t* __restrict__ hp,
                                                  float* __restrict__ out) {
    int t = threadIdx.x;
    int wave = t >> 6, lane = t & 63;
    int part = blockIdx.x & 7;
    int local = (blockIdx.x >> 3) * 4 + wave;
    if (local >= PART) return;
    int d = part * PART + local;
    int s0 = off[d], s1 = off[d + 1];

    __shared__ int   s_i[4][64];
    __shared__ f32x4 s_p[4][64];

    int l15 = lane & 15, grp = lane >> 4;
    int hd = l15 >> 2;
    f32x4 ad = *(const f32x4*)(adst + d * 4);
    float sum[4] = {0.f, 0.f, 0.f, 0.f};
    f32x4 accA = {0.f, 0.f, 0.f, 0.f}, accB = {0.f, 0.f, 0.f, 0.f};

    for (int base = s0; base < s1; base += 64) {
        int n = min(64, s1 - base);
        int e = base + lane;
        bool ok = e < s1;
        int s = ok ? csr[e] : 0;
        f32x4 p4 = {0.f, 0.f, 0.f, 0.f};
        if (ok) {
            f32x4 as = *(const f32x4*)(asrc + s * 4);
#pragma unroll
            for (int hh = 0; hh < 4; ++hh) {
                float v = as[hh] + ad[hh];
                v = v > 0.f ? v : NEG_SLOPE * v;
                v = fminf(v, 80.f);
                float p = __expf(v);
                p4[hh] = p;
                sum[hh] += p;
            }
        }
        s_i[wave][lane] = s;
        s_p[wave][lane] = p4;
        __builtin_amdgcn_wave_barrier();
        int iters = (n + 3) >> 2;
#pragma unroll 2
        for (int it = 0; it < iters; ++it) {
            int ei = it * 4 + grp;
            int se = s_i[wave][ei];
            float w = s_p[wave][ei][hd];
            const char* rp = (const char*)hp + ((size_t)se << 8) + l15 * 16;
            uint4 u = *(const uint4*)rp;
            accA[0] += w * __uint_as_float(u.x << 16);
            accA[1] += w * __uint_as_float(u.x & 0xFFFF0000u);
            accA[2] += w * __uint_as_float(u.y << 16);
            accA[3] += w * __uint_as_float(u.y & 0xFFFF0000u);
            accB[0] += w * __uint_as_float(u.z << 16);
            accB[1] += w * __uint_as_float(u.z & 0xFFFF0000u);
            accB[2] += w * __uint_as_float(u.w << 16);
            accB[3] += w * __uint_as_float(u.w & 0xFFFF0000u);
        }
        __builtin_amdgcn_wave_barrier();
    }
#pragma unroll
    for (int o = 16; o < 64; o <<= 1) {
#pragma unroll
        for (int j = 0; j < 4; ++j) {
            accA[j] += __shfl_xor(accA[j], o, 64);
            accB[j] += __shfl_xor(accB[j], o, 64);
        }
    }
#pragma unroll
    for (int o = 1; o < 64; o <<= 1) {
#pragma unroll
        for (int hh = 0; hh < 4; ++hh) sum[hh] += __shfl_xor(sum[hh], o, 64);
    }
    if (grp == 0) {
        float den = sum[hd];
        float inv = (den > 0.f) ? 1.f / den : 0.f;
        f32x4 r0, r1;
#pragma unroll
        for (int j = 0; j < 4; ++j) { r0[j] = accA[j] * inv; r1[j] = accB[j] * inv; }
        float* op = out + (size_t)d * OUT_D + l15 * 8;
        *(f32x4*)op = r0;
        *(f32x4*)(op + 4) = r1;
    }
}

// ---------------------------------------------------------------------------
extern "C" void kernel_launch(void* const* d_in, const int* in_sizes, int n_in,
                              void* d_out, int out_size, void* d_ws, size_t ws_size,
                              hipStream_t stream) {
    const float* h   = (const float*)d_in[0];
    const int*   adj = (const int*)d_in[1];
    const float* W   = (const float*)d_in[2];
    const float* a   = (const float*)d_in[3];
    float*       out = (float*)d_out;

    const int* src = adj;
    const int* dst = adj + N_EDGES;

    char* ws = (char*)d_ws;
    size_t o = 0;
    auto alloc = [&](size_t bytes) -> void* {
        void* p = ws + o;
        o = (o + bytes + 255) & ~(size_t)255;
        return p;
    };
    ushort_t* hp     = (ushort_t*)alloc((size_t)N_NODES * OUT_D * 2);  // 12.8 MB bf16
    ushort_t* wt     = (ushort_t*)alloc((size_t)32768 * 2);            // 64 KB
    float*    asrc   = (float*)alloc((size_t)N_NODES * 4 * 4);
    float*    adstp  = (float*)alloc((size_t)N_NODES * 4 * 4);
    int*      deg8   = (int*)alloc((size_t)8 * NP * 4);                // 1.6 MB
    int*      deg    = (int*)alloc((size_t)NP * 4);
    int*      off    = (int*)alloc((size_t)(NP + 256) * 4);
    int*      cursor = (int*)alloc((size_t)NP * 4);
    int*      csr    = (int*)alloc((size_t)N_EDGES * 4);               // 6.4 MB
    int*      bsum   = (int*)alloc((size_t)SCAN_NB * 4);
    int*      bbase  = (int*)alloc((size_t)SCAN_NB * 4);
    int*      tail8  = (int*)alloc(8 * 4);
    uint2*    binbuf = (uint2*)alloc((size_t)8 * CAPP * 8);            // 13.1 MB

    hipMemsetAsync(deg8, 0, (size_t)8 * NP * 4, stream);
    hipMemsetAsync(tail8, 0, 8 * 4, stream);

    const int chunks = (N_EDGES + 2047) / 2048;   // 782

    wprep_kernel<<<32, 256, 0, stream>>>(W, wt);
    gemm_kernel<<<(N_NODES + 127) / 128, 256, 0, stream>>>(h, wt, a, hp, asrc, adstp);
    bin_kernel<<<chunks, 256, 0, stream>>>(src, dst, deg8, tail8, binbuf);
    scan_part_kernel<<<SCAN_NB, 256, 0, stream>>>(deg8, deg, bsum);
    scan_top_kernel<<<1, 64, 0, stream>>>(bsum, bbase);
    scan_final_kernel<<<SCAN_NB, 256, 0, stream>>>(deg, bbase, off, cursor);
    scatter2_kernel<<<104 * 8, 256, 0, stream>>>(binbuf, tail8, cursor, csr);
    agg_kernel<<<((PART + 3) / 4) * 8, 256, 0, stream>>>(off, csr, asrc, adstp, hp, out);
}

// Round 8
// 203.929 us; speedup vs baseline: 1.5788x; 1.5788x over previous
//
#include <hip/hip_runtime.h>

#define N_NODES 50000
#define N_EDGES 1600000
#define IN_DIM  256
#define OUT_D   128   // N_HEADS * OUT_DIM
#define NEG_SLOPE 0.2f
#define NBIN 256      // dst bins
#define BINW 196      // nodes per bin (256*196 = 50176 >= N_NODES)
#define CAP  8192     // per-bin edge capacity (mean 6270, sigma ~79 -> +24 sigma)
#define KDUP 4        // workgroups per bin in aggB
#define NPW  49       // nodes per workgroup (49*4 = 196)

typedef unsigned short ushort_t;
typedef short bf16x8 __attribute__((ext_vector_type(8)));
typedef float f32x4 __attribute__((ext_vector_type(4)));

__device__ __forceinline__ ushort_t f2bf(float f) {
    unsigned u = __float_as_uint(f);
    u = (u + 0x7FFF + ((u >> 16) & 1)) >> 16;   // RNE
    return (ushort_t)u;
}

// ---------------------------------------------------------------------------
// K0b: W fp32 [256][128] -> wt bf16, transposed n-major with 16B XOR swizzle.
__global__ __launch_bounds__(256) void wprep_kernel(const float* __restrict__ W,
                                                    ushort_t* __restrict__ wt) {
    int i0 = (blockIdx.x * 256 + threadIdx.x) * 4;   // grid 32 -> covers 32768
    f32x4 v = *(const f32x4*)(W + i0);
    int k = i0 >> 7;
    int n0 = i0 & 127;
    int byte_in_row = 2 * k;
#pragma unroll
    for (int j = 0; j < 4; ++j) {
        int n = n0 + j;
        int sw = ((byte_in_row & ~15) ^ ((n & 7) << 4)) | (byte_in_row & 15);
        wt[(n << 8) + (sw >> 1)] = f2bf(v[j]);
    }
}

// ---------------------------------------------------------------------------
// K1: h_prime = bf16(h) @ bf16(W) via MFMA; epilogue also produces asrc/adst
//     attention logit halves from the fp32 accumulators.
__global__ __launch_bounds__(256) void gemm_kernel(const float* __restrict__ h,
                                                   const ushort_t* __restrict__ wt,
                                                   const float* __restrict__ a,
                                                   ushort_t* __restrict__ hp,
                                                   float* __restrict__ asrc,
                                                   float* __restrict__ adst) {
    __shared__ ushort_t sW[32768];  // 64 KB
    int t = threadIdx.x;
    for (int i = t * 8; i < 32768; i += 2048)
        *(bf16x8*)(sW + i) = *(const bf16x8*)(wt + i);
    __syncthreads();

    int wave = t >> 6, lane = t & 63;
    int l15 = lane & 15, quad = lane >> 4;
    int rowbase = blockIdx.x * 128 + wave * 16;

    f32x4 acc[2][8] = {};
#pragma unroll
    for (int ks = 0; ks < 8; ++ks) {
        bf16x8 af[2];
#pragma unroll
        for (int rt = 0; rt < 2; ++rt) {
            int arow = rowbase + rt * 64 + l15;
            if (arow >= N_NODES) arow = N_NODES - 1;
            const float* ap = h + (size_t)arow * IN_DIM + quad * 8 + ks * 32;
            f32x4 lo = *(const f32x4*)ap;
            f32x4 hi = *(const f32x4*)(ap + 4);
#pragma unroll
            for (int j = 0; j < 4; ++j) {
                af[rt][j]     = (short)f2bf(lo[j]);
                af[rt][4 + j] = (short)f2bf(hi[j]);
            }
        }
        int koff = ks * 64 + quad * 16;
#pragma unroll
        for (int tn = 0; tn < 8; ++tn) {
            int n = tn * 16 + l15;
            int swz = koff ^ ((n & 7) << 4);
            bf16x8 bfr = *(const bf16x8*)((const char*)sW + n * 512 + swz);
            acc[0][tn] = __builtin_amdgcn_mfma_f32_16x16x32_bf16(af[0], bfr, acc[0][tn], 0, 0, 0);
            acc[1][tn] = __builtin_amdgcn_mfma_f32_16x16x32_bf16(af[1], bfr, acc[1][tn], 0, 0, 0);
        }
    }

    float aS[8], aD[8];
#pragma unroll
    for (int tn = 0; tn < 8; ++tn) {
        int col = tn * 16 + l15;
        int dd = col & 31, hh = col >> 5;
        aS[tn] = a[dd * 4 + hh];
        aD[tn] = a[(32 + dd) * 4 + hh];
    }

#pragma unroll
    for (int rt = 0; rt < 2; ++rt)
#pragma unroll
        for (int r = 0; r < 4; ++r) {
            int row = rowbase + rt * 64 + quad * 4 + r;
            float pS[4] = {0.f, 0.f, 0.f, 0.f}, pD[4] = {0.f, 0.f, 0.f, 0.f};
#pragma unroll
            for (int tn = 0; tn < 8; ++tn) {
                float v = acc[rt][tn][r];
                pS[tn >> 1] += v * aS[tn];
                pD[tn >> 1] += v * aD[tn];
            }
#pragma unroll
            for (int o = 1; o < 16; o <<= 1) {
#pragma unroll
                for (int hh = 0; hh < 4; ++hh) {
                    pS[hh] += __shfl_xor(pS[hh], o, 16);
                    pD[hh] += __shfl_xor(pD[hh], o, 16);
                }
            }
            if (row < N_NODES) {
                if (l15 == 0) { f32x4 v = {pS[0], pS[1], pS[2], pS[3]}; *(f32x4*)(asrc + row * 4) = v; }
                if (l15 == 1) { f32x4 v = {pD[0], pD[1], pD[2], pD[3]}; *(f32x4*)(adst + row * 4) = v; }
            }
        }

#pragma unroll
    for (int rt = 0; rt < 2; ++rt)
#pragma unroll
        for (int tn = 0; tn < 8; ++tn) {
            int col = tn * 16 + l15;
#pragma unroll
            for (int r = 0; r < 4; ++r) {
                int row = rowbase + rt * 64 + quad * 4 + r;
                if (row < N_NODES) hp[(size_t)row * OUT_D + col] = f2bf(acc[rt][tn][r]);
            }
        }
}

// ---------------------------------------------------------------------------
// K3 (binA): 196 blocks x 8192 edges. LDS histogram over 256 dst-bins,
//   ONE global atomic per (block,bin) = 50K total. LDS-staged scatter so
//   binbuf writes are ~128B coalesced runs of packed 4B entries.
__global__ __launch_bounds__(256) void binA_kernel(const int* __restrict__ src,
                                                   const int* __restrict__ dst,
                                                   int* __restrict__ tail,
                                                   unsigned* __restrict__ binbuf) {
    __shared__ unsigned stage[8192];    // 32 KB
    __shared__ int cnt[256], lcnt[256], lbase[256], gbase[256], sc[256];
    int t = threadIdx.x;
    cnt[t] = 0; lcnt[t] = 0;
    __syncthreads();

    int blockbase = blockIdx.x * 8192;
    int n = min(8192, N_EDGES - blockbase);
    int e0 = blockbase + t * 32;
    int d[32], s[32];
#pragma unroll
    for (int q = 0; q < 8; ++q) {
        if (t * 32 + q * 4 + 4 <= n) {
            int4 dv = *(const int4*)(dst + e0 + q * 4);
            int4 sv = *(const int4*)(src + e0 + q * 4);
            d[q*4+0]=dv.x; d[q*4+1]=dv.y; d[q*4+2]=dv.z; d[q*4+3]=dv.w;
            s[q*4+0]=sv.x; s[q*4+1]=sv.y; s[q*4+2]=sv.z; s[q*4+3]=sv.w;
        } else {
#pragma unroll
            for (int r = 0; r < 4; ++r) {
                int g = t * 32 + q * 4 + r;
                d[q*4+r] = (g < n) ? dst[e0 + q*4 + r] : -1;
                s[q*4+r] = (g < n) ? src[e0 + q*4 + r] : 0;
            }
        }
    }
#pragma unroll
    for (int j = 0; j < 32; ++j)
        if (d[j] >= 0) atomicAdd(&cnt[(unsigned)d[j] / BINW], 1);
    __syncthreads();
    gbase[t] = atomicAdd(&tail[t], cnt[t]);     // the ONLY global atomics
    sc[t] = cnt[t]; __syncthreads();
#pragma unroll
    for (int off = 1; off < 256; off <<= 1) {
        int v = (t >= off) ? sc[t - off] : 0;
        __syncthreads();
        sc[t] += v;
        __syncthreads();
    }
    lbase[t] = sc[t] - cnt[t];
    __syncthreads();
#pragma unroll
    for (int j = 0; j < 32; ++j) {
        if (d[j] >= 0) {
            unsigned p = (unsigned)d[j] / BINW;
            unsigned ldst = (unsigned)d[j] - p * BINW;
            int pos = lbase[p] + atomicAdd(&lcnt[p], 1);
            stage[pos] = (unsigned)s[j] | (ldst << 16) | (p << 24);
        }
    }
    __syncthreads();
    for (int i = t; i < n; i += 256) {
        unsigned v = stage[i];
        unsigned p = v >> 24;
        int pos = gbase[p] + (i - lbase[p]);
        if (pos < CAP) binbuf[(size_t)p * CAP + pos] = v & 0xFFFFFFu;
    }
}

// ---------------------------------------------------------------------------
// K6 (aggB): fused local-CSR build + softmax aggregation. 4 workgroups/bin;
//   each rebuilds the bin's CSR in LDS (LDS atomics only), then aggregates
//   its 49-node slice with the wave-per-node gather loop.
__global__ __launch_bounds__(256) void aggB_kernel(const unsigned* __restrict__ binbuf,
                                                   const int* __restrict__ tail,
                                                   const float* __restrict__ asrc,
                                                   const float* __restrict__ adst,
                                                   const ushort_t* __restrict__ hp,
                                                   float* __restrict__ out) {
    int b = blockIdx.x >> 2, j = blockIdx.x & 3;
    __shared__ ushort_t lcsr[CAP];                 // 16 KB
    __shared__ int cnt[256], sc[256], excl[256], lcur[256];
    __shared__ int   s_i[4][64];
    __shared__ f32x4 s_p[4][64];
    int t = threadIdx.x;
    int count = min(tail[b], CAP);
    const unsigned* buf = binbuf + (size_t)b * CAP;

    cnt[t] = 0;
    __syncthreads();
    for (int i = t; i < count; i += 256)
        atomicAdd(&cnt[(buf[i] >> 16) & 0xFF], 1);
    __syncthreads();
    sc[t] = cnt[t]; __syncthreads();
#pragma unroll
    for (int off = 1; off < 256; off <<= 1) {
        int v = (t >= off) ? sc[t - off] : 0;
        __syncthreads();
        sc[t] += v;
        __syncthreads();
    }
    excl[t] = sc[t] - cnt[t];
    lcur[t] = excl[t];
    __syncthreads();
    for (int i = t; i < count; i += 256) {
        unsigned v = buf[i];
        int ld = (v >> 16) & 0xFF;
        int pos = atomicAdd(&lcur[ld], 1);
        lcsr[pos] = (ushort_t)(v & 0xFFFF);
    }
    __syncthreads();

    int wave = t >> 6, lane = t & 63;
    int l15 = lane & 15, grp = lane >> 4;
    int hd = l15 >> 2;

    for (int ld = j * NPW + wave; ld < j * NPW + NPW; ld += 4) {
        int d = b * BINW + ld;
        if (d >= N_NODES) continue;                 // wave-uniform
        int s0 = excl[ld], s1 = sc[ld];
        f32x4 ad = *(const f32x4*)(adst + d * 4);
        float sum[4] = {0.f, 0.f, 0.f, 0.f};
        f32x4 accA = {0.f, 0.f, 0.f, 0.f}, accB = {0.f, 0.f, 0.f, 0.f};

        for (int base = s0; base < s1; base += 64) {
            int n = min(64, s1 - base);
            int e = base + lane;
            bool ok = e < s1;
            int s = ok ? (int)lcsr[e] : 0;
            f32x4 p4 = {0.f, 0.f, 0.f, 0.f};
            if (ok) {
                f32x4 as = *(const f32x4*)(asrc + s * 4);
#pragma unroll
                for (int hh = 0; hh < 4; ++hh) {
                    float v = as[hh] + ad[hh];
                    v = v > 0.f ? v : NEG_SLOPE * v;
                    v = fminf(v, 80.f);
                    float p = __expf(v);
                    p4[hh] = p;
                    sum[hh] += p;
                }
            }
            s_i[wave][lane] = s;
            s_p[wave][lane] = p4;
            __builtin_amdgcn_wave_barrier();
            int iters = (n + 3) >> 2;
#pragma unroll 2
            for (int it = 0; it < iters; ++it) {
                int ei = it * 4 + grp;
                int se = s_i[wave][ei];
                float w = s_p[wave][ei][hd];
                const char* rp = (const char*)hp + ((size_t)se << 8) + l15 * 16;
                uint4 u = *(const uint4*)rp;
                accA[0] += w * __uint_as_float(u.x << 16);
                accA[1] += w * __uint_as_float(u.x & 0xFFFF0000u);
                accA[2] += w * __uint_as_float(u.y << 16);
                accA[3] += w * __uint_as_float(u.y & 0xFFFF0000u);
                accB[0] += w * __uint_as_float(u.z << 16);
                accB[1] += w * __uint_as_float(u.z & 0xFFFF0000u);
                accB[2] += w * __uint_as_float(u.w << 16);
                accB[3] += w * __uint_as_float(u.w & 0xFFFF0000u);
            }
            __builtin_amdgcn_wave_barrier();
        }
#pragma unroll
        for (int o = 16; o < 64; o <<= 1) {
#pragma unroll
            for (int q = 0; q < 4; ++q) {
                accA[q] += __shfl_xor(accA[q], o, 64);
                accB[q] += __shfl_xor(accB[q], o, 64);
            }
        }
#pragma unroll
        for (int o = 1; o < 64; o <<= 1) {
#pragma unroll
            for (int hh = 0; hh < 4; ++hh) sum[hh] += __shfl_xor(sum[hh], o, 64);
        }
        if (grp == 0) {
            float den = sum[hd];
            float inv = (den > 0.f) ? 1.f / den : 0.f;
            f32x4 r0, r1;
#pragma unroll
            for (int q = 0; q < 4; ++q) { r0[q] = accA[q] * inv; r1[q] = accB[q] * inv; }
            float* op = out + (size_t)d * OUT_D + l15 * 8;
            *(f32x4*)op = r0;
            *(f32x4*)(op + 4) = r1;
        }
    }
}

// ---------------------------------------------------------------------------
extern "C" void kernel_launch(void* const* d_in, const int* in_sizes, int n_in,
                              void* d_out, int out_size, void* d_ws, size_t ws_size,
                              hipStream_t stream) {
    const float* h   = (const float*)d_in[0];
    const int*   adj = (const int*)d_in[1];
    const float* W   = (const float*)d_in[2];
    const float* a   = (const float*)d_in[3];
    float*       out = (float*)d_out;

    const int* src = adj;
    const int* dst = adj + N_EDGES;

    char* ws = (char*)d_ws;
    size_t o = 0;
    auto alloc = [&](size_t bytes) -> void* {
        void* p = ws + o;
        o = (o + bytes + 255) & ~(size_t)255;
        return p;
    };
    ushort_t* hp     = (ushort_t*)alloc((size_t)N_NODES * OUT_D * 2);  // 12.8 MB bf16
    ushort_t* wt     = (ushort_t*)alloc((size_t)32768 * 2);            // 64 KB
    float*    asrc   = (float*)alloc((size_t)N_NODES * 4 * 4);
    float*    adstp  = (float*)alloc((size_t)N_NODES * 4 * 4);
    int*      tail   = (int*)alloc((size_t)NBIN * 4);
    unsigned* binbuf = (unsigned*)alloc((size_t)NBIN * CAP * 4);       // 8 MB

    hipMemsetAsync(tail, 0, (size_t)NBIN * 4, stream);

    wprep_kernel<<<32, 256, 0, stream>>>(W, wt);
    gemm_kernel<<<(N_NODES + 127) / 128, 256, 0, stream>>>(h, wt, a, hp, asrc, adstp);
    binA_kernel<<<(N_EDGES + 8191) / 8192, 256, 0, stream>>>(src, dst, tail, binbuf);
    aggB_kernel<<<NBIN * KDUP, 256, 0, stream>>>(binbuf, tail, asrc, adstp, hp, out);
}